// Round 9
// baseline (166.401 us; speedup 1.0000x reference)
//
#include <hip/hip_runtime.h>
#include <math.h>

// B,S,D,V,N_BLOCKS = 4096,128,9,5,4
constexpr int Bn = 4096;
constexpr int Sn = 128;
constexpr int Dn = 9;
constexpr int Vn = 5;
constexpr int NBn = 4;
constexpr int WPB = 2;   // batches (=waves) per 128-thread block

typedef float f4 __attribute__((ext_vector_type(4)));
typedef _Float16 h8 __attribute__((ext_vector_type(8)));   // MFMA operand
typedef __fp16   h2 __attribute__((ext_vector_type(2)));   // cvt_pkrtz result
typedef __fp16   hv8 __attribute__((ext_vector_type(8)));
typedef unsigned u4v __attribute__((ext_vector_type(4)));
typedef short    s4v __attribute__((ext_vector_type(4)));

// LDS (bytes):
//  MBs [4][16][32] fp16 : M~ = qscale*Wq^T*Wk per layer (col9 = qscale*Wk^T*bq),
//                         rows n, slots [Mh|Mh|Ml|0(27-31)]; rows 10-15 garbage (unused D cols)
//  VBs [4][16][32] fp16 : Wv^T per layer, same format
//  per batch (per wave), 15872 B:
//    XB [128][40] fp16  : X rows [Xh(0-8)|Xl(9-17)|Xhdup(18-26)|0(27-29)|ch,cl(30-31)]
//                         stride 80B -> conflict-free b128 frag reads. O overwrites in place.
//    VF [16][136] fp16  : V^T (dims 9-15 uninit -> contained in unused D rows)
//    SCR [16][40] fp16  : per-q-tile G rows [Gh|Gh|0|0|1,1]; slots 18-31 static
// ZERO __syncthreads after prologue: all handoffs are wave-local (in-order LDS).
constexpr int MB_OFF = 0;            // 4096
constexpr int VB_OFF = 4096;         // 4096
constexpr int BATCH_OFF = 8192;      // + w*15872
constexpr int BATCH_BYTES = 15872;
constexpr int SMEM_BYTES = 8192 + WPB * 15872;   // 39936 -> 4 blocks/CU

static __device__ __forceinline__ void split_hl(float v, short& h, short& l) {
    _Float16 hv = (_Float16)v;
    h = __builtin_bit_cast(short, hv);
    l = __builtin_bit_cast(short, (_Float16)(v - (float)hv));
}

__global__ __launch_bounds__(128, 2) void bert_kernel(
    const int*   __restrict__ tokens,
    const float* __restrict__ emb,
    const float* __restrict__ Wq, const float* __restrict__ bq,
    const float* __restrict__ Wk, const float* __restrict__ bk,
    const float* __restrict__ Wv, const float* __restrict__ bv,
    const float* __restrict__ Wout, const float* __restrict__ bout,
    float*       __restrict__ out)
{
    __shared__ __align__(16) char smem[SMEM_BYTES];
    short* MBs = (short*)(smem + MB_OFF);
    short* VBs = (short*)(smem + VB_OFF);

    const int tid = threadIdx.x;         // 0..127
    const int t   = tid & 63;
    const int w   = tid >> 6;            // wave = local batch
    const int col = t & 15;
    const int g   = t >> 4;
    const int b   = blockIdx.x * WPB + w;
    const float qscale = (1.0f / 3.0f) * 1.44269504f;   // 1/sqrt(D) * log2(e)

    short* XB  = (short*)(smem + BATCH_OFF + w * BATCH_BYTES);
    short* VF  = XB + 5120;    // shorts
    short* SCR = XB + 7296;

    // ---- build M~ (all 4 layers), VB, zero pad slots ----
    for (int i = tid; i < 360; i += 128) {
        const int l = i / 90, j = i % 90, d = j % 9, n = j / 9;  // n 0..9 (9 = c col)
        const float* wq  = Wq + l * 81;
        const float* wk  = Wk + l * 81;
        const float* bqi = bq + l * 9;
        float a = 0.0f;
        if (n < 9) {
            #pragma unroll
            for (int e = 0; e < 9; ++e) a = fmaf(wq[e * 9 + d], wk[e * 9 + n], a);
        } else {
            #pragma unroll
            for (int e = 0; e < 9; ++e) a = fmaf(wk[e * 9 + d], bqi[e], a);
        }
        a *= qscale;
        short hh, ll; split_hl(a, hh, ll);
        short* row = MBs + l * 512 + n * 32;
        row[d] = hh; row[9 + d] = hh; row[18 + d] = ll;
    }
    for (int i = tid; i < 200; i += 128) {   // MB slots 27-31, rows n 0..9
        const int l = i / 50, j = i % 50, n = j / 5, s = 27 + j % 5;
        MBs[l * 512 + n * 32 + s] = 0;
    }
    for (int i = tid; i < 324; i += 128) {   // VB: Wv^T rows e 0..8
        const int l = i / 81, j = i % 81, d = j % 9, e = j / 9;
        short hh, ll; split_hl(Wv[l * 81 + e * 9 + d], hh, ll);
        short* row = VBs + l * 512 + e * 32;
        row[d] = hh; row[9 + d] = hh; row[18 + d] = ll;
    }
    for (int i = tid; i < 180; i += 128) {   // VB slots 27-31, rows 0..8
        const int l = i / 45, j = i % 45, n = j / 5, s = 27 + j % 5;
        VBs[l * 512 + n * 32 + s] = 0;
    }

    // ---- per-wave: scratch static slots + embed+posenc -> XB ----
    if (t < 16) {
        short* sr = SCR + t * 40;
        *(unsigned*)(sr + 18) = 0u; *(unsigned*)(sr + 20) = 0u;
        *(unsigned*)(sr + 22) = 0u; *(unsigned*)(sr + 24) = 0u;
        *(unsigned*)(sr + 26) = 0u; *(unsigned*)(sr + 28) = 0u;
        *(unsigned*)(sr + 30) = 0x3C003C00u;   // fp16 1.0, 1.0
    }
    {
        const float inv_freq[Dn] = {
            1.0f, 1.0f, 0.1291549665f, 0.1291549665f,
            0.0166810054f, 0.0166810054f, 0.0021544347f, 0.0021544347f,
            0.0002782559f
        };
        #pragma unroll
        for (int rr = 0; rr < 2; ++rr) {
            const int r = t + rr * 64;
            const int tok = tokens[b * Sn + r];
            unsigned short sl[32];
            #pragma unroll
            for (int d = 0; d < Dn; ++d) {
                const float a = (float)r * inv_freq[d];
                const float p = (d & 1) ? __cosf(a) : __sinf(a);
                short hh, ll; split_hl(emb[tok * Dn + d] + p, hh, ll);
                sl[d] = (unsigned short)hh;
                sl[9 + d] = (unsigned short)ll;
                sl[18 + d] = (unsigned short)hh;
            }
            #pragma unroll
            for (int d = 27; d < 32; ++d) sl[d] = 0;
            unsigned wb[16];
            #pragma unroll
            for (int j = 0; j < 16; ++j)
                wb[j] = (unsigned)sl[2 * j] | ((unsigned)sl[2 * j + 1] << 16);
            u4v* rp = (u4v*)(XB + r * 40);
            rp[0] = (u4v){wb[0], wb[1], wb[2], wb[3]};
            rp[1] = (u4v){wb[4], wb[5], wb[6], wb[7]};
            rp[2] = (u4v){wb[8], wb[9], wb[10], wb[11]};
            rp[3] = (u4v){wb[12], wb[13], wb[14], wb[15]};
        }
    }
    __syncthreads();   // the ONLY barrier: MBs/VBs shared by both waves

    #pragma unroll 1
    for (int it = 0; it < NBn; ++it) {
        const short* MBl = MBs + it * 512;
        const short* VBl = VBs + it * 512;
        h8 mbf = *(const h8*)(MBl + col * 32 + g * 8);
        h8 vbf = *(const h8*)(VBl + col * 32 + g * 8);
        const float bvv = (col < 9) ? bv[it * 9 + col] : 0.0f;
        f4 cinit = {bvv, bvv, bvv, bvv};

        // ---- pre-pass: G tiles -> regs (C-layout), V -> VF, c -> XB[30..31] ----
        f4 gt[8];
        #pragma unroll
        for (int kt = 0; kt < 8; ++kt) {
            h8 xa = *(const h8*)(XB + (kt * 16 + col) * 40 + g * 8);  // stale c ok (MB slots 27-31 = 0)
            gt[kt] = __builtin_amdgcn_mfma_f32_16x16x32_f16(xa, mbf, (f4)(0.0f), 0, 0, 0);
            f4 vt   = __builtin_amdgcn_mfma_f32_16x16x32_f16(xa, vbf, cinit, 0, 0, 0);
            const int r0 = kt * 16 + 4 * g;
            if (col < 9) {
                #pragma unroll
                for (int rr = 0; rr < 4; ++rr)
                    VF[col * 136 + r0 + rr] = __builtin_bit_cast(short, (_Float16)vt[rr]);
            } else if (col == 9) {   // c[r] -> XB row r slots 30/31 (hi|lo)
                #pragma unroll
                for (int rr = 0; rr < 4; ++rr) {
                    short hh, ll; split_hl(gt[kt][rr], hh, ll);
                    *(unsigned*)(XB + (r0 + rr) * 40 + 30) =
                        (unsigned)(unsigned short)hh | ((unsigned)(unsigned short)ll << 16);
                }
            }
        }

        // ---- fresh K-frags (with new c) + V^T A-frags ----
        h8 kfr[8];
        #pragma unroll
        for (int kt = 0; kt < 8; ++kt)
            kfr[kt] = *(const h8*)(XB + (kt * 16 + col) * 40 + g * 8);
        h8 vfr[4];   // slot(g,j) <-> key 16*(2s+(j>>2)) + 4g + (j&3)
        #pragma unroll
        for (int s = 0; s < 4; ++s) {
            const short* p0 = VF + col * 136 + 32 * s + 4 * g;
            s4v va = *(const s4v*)p0;
            s4v vb2 = *(const s4v*)(p0 + 16);
            vfr[s] = __builtin_bit_cast(h8,
                __builtin_shufflevector(va, vb2, 0, 1, 2, 3, 4, 5, 6, 7));
        }

        // ---- per q-tile: G->scratch, 1-MFMA scores, no-max softmax, PV ----
        f4 oh[8];
        #pragma unroll
        for (int qt = 0; qt < 8; ++qt) {
            if (col < 9) {   // G fp16-single: slots [col] and [9+col]
                #pragma unroll
                for (int rr = 0; rr < 4; ++rr) {
                    short hh = __builtin_bit_cast(short, (_Float16)gt[qt][rr]);
                    SCR[(4 * g + rr) * 40 + col] = hh;
                    SCR[(4 * g + rr) * 40 + 9 + col] = hh;
                }
            }
            h8 bg = *(const h8*)(SCR + col * 40 + g * 8);

            f4 acc[8];
            #pragma unroll
            for (int kt = 0; kt < 8; ++kt)
                acc[kt] = __builtin_amdgcn_mfma_f32_16x16x32_f16(kfr[kt], bg, (f4)(0.0f), 0, 0, 0);

            // exp2 direct (log2-domain scores, |s| << 126), normalize in f32
            float sm = 0.0f;
            #pragma unroll
            for (int kt = 0; kt < 8; ++kt)
                #pragma unroll
                for (int rr = 0; rr < 4; ++rr) {
                    float e2 = __builtin_amdgcn_exp2f(acc[kt][rr]);
                    acc[kt][rr] = e2;
                    sm += e2;
                }
            sm += __shfl_xor(sm, 16);
            sm += __shfl_xor(sm, 32);
            const float rl = 1.0f / sm;

            f4 ac0 = (f4)(0.0f), ac1 = (f4)(0.0f);
            #pragma unroll
            for (int s = 0; s < 4; ++s) {
                u4v up = (u4v){
                    __builtin_bit_cast(unsigned, __builtin_amdgcn_cvt_pkrtz(acc[2*s][0]*rl,   acc[2*s][1]*rl)),
                    __builtin_bit_cast(unsigned, __builtin_amdgcn_cvt_pkrtz(acc[2*s][2]*rl,   acc[2*s][3]*rl)),
                    __builtin_bit_cast(unsigned, __builtin_amdgcn_cvt_pkrtz(acc[2*s+1][0]*rl, acc[2*s+1][1]*rl)),
                    __builtin_bit_cast(unsigned, __builtin_amdgcn_cvt_pkrtz(acc[2*s+1][2]*rl, acc[2*s+1][3]*rl)) };
                if (s & 1)
                    ac1 = __builtin_amdgcn_mfma_f32_16x16x32_f16(vfr[s], __builtin_bit_cast(h8, up), ac1, 0, 0, 0);
                else
                    ac0 = __builtin_amdgcn_mfma_f32_16x16x32_f16(vfr[s], __builtin_bit_cast(h8, up), ac0, 0, 0, 0);
            }
            oh[qt] = ac0 + ac1;
        }

        // ---- O overwrites XB in place (K-frags already in regs) ----
        #pragma unroll
        for (int qt = 0; qt < 8; ++qt) {
            const int q = qt * 16 + col;
            f4 oac = oh[qt];
            short* rowp = XB + q * 40;
            if (g < 2) {
                h2 p01 = __builtin_amdgcn_cvt_pkrtz(oac.x, oac.y);
                h2 p23 = __builtin_amdgcn_cvt_pkrtz(oac.z, oac.w);
                *(unsigned*)(rowp + 4 * g)          = __builtin_bit_cast(unsigned, p01);
                *(unsigned*)(rowp + 4 * g + 2)      = __builtin_bit_cast(unsigned, p23);
                *(unsigned*)(rowp + 18 + 4 * g)     = __builtin_bit_cast(unsigned, p01);
                *(unsigned*)(rowp + 18 + 4 * g + 2) = __builtin_bit_cast(unsigned, p23);
                rowp[9 + 4 * g + 0] = __builtin_bit_cast(short, (_Float16)(oac.x - (float)p01.x));
                rowp[9 + 4 * g + 1] = __builtin_bit_cast(short, (_Float16)(oac.y - (float)p01.y));
                rowp[9 + 4 * g + 2] = __builtin_bit_cast(short, (_Float16)(oac.z - (float)p23.x));
                rowp[9 + 4 * g + 3] = __builtin_bit_cast(short, (_Float16)(oac.w - (float)p23.y));
            } else if (g == 2) {
                short hh, ll; split_hl(oac.x, hh, ll);
                rowp[8] = hh; rowp[17] = ll; rowp[26] = hh;
            }
        }
    }

    // ---- logits + log_softmax (wave-local; no barrier needed) ----
    #pragma unroll
    for (int rr = 0; rr < 2; ++rr) {
        const int r = t + rr * 64;
        const short* rowp = XB + r * 40;
        hv8 ha = __builtin_bit_cast(hv8, *(const u4v*)rowp);            // slots 0..7
        hv8 hb = __builtin_bit_cast(hv8, *(const u4v*)(rowp + 8));      // slots 8..15
        h2  hc = __builtin_bit_cast(h2, *(const unsigned*)(rowp + 16)); // slots 16,17
        float x[9];
        x[0] = (float)ha[0] + (float)hb[1];
        x[1] = (float)ha[1] + (float)hb[2];
        x[2] = (float)ha[2] + (float)hb[3];
        x[3] = (float)ha[3] + (float)hb[4];
        x[4] = (float)ha[4] + (float)hb[5];
        x[5] = (float)ha[5] + (float)hb[6];
        x[6] = (float)ha[6] + (float)hb[7];
        x[7] = (float)ha[7] + (float)hc.x;
        x[8] = (float)hb[0] + (float)hc.y;
        float lg[Vn];
        #pragma unroll
        for (int v = 0; v < Vn; ++v) {
            float a = bout[v];
            #pragma unroll
            for (int d = 0; d < Dn; ++d) a = fmaf(x[d], Wout[v * Dn + d], a);
            lg[v] = a;
        }
        float mm = lg[0];
        #pragma unroll
        for (int v = 1; v < Vn; ++v) mm = fmaxf(mm, lg[v]);
        float sum = 0.0f;
        #pragma unroll
        for (int v = 0; v < Vn; ++v)
            sum += __builtin_amdgcn_exp2f((lg[v] - mm) * 1.44269504f);
        const float lse = __builtin_amdgcn_logf(sum) * 0.69314718f + mm;
        float* op = out + ((size_t)b * Sn + r) * Vn;
        #pragma unroll
        for (int v = 0; v < Vn; ++v) op[v] = lg[v] - lse;
    }
}

extern "C" void kernel_launch(void* const* d_in, const int* in_sizes, int n_in,
                              void* d_out, int out_size, void* d_ws, size_t ws_size,
                              hipStream_t stream) {
    const int*   tokens = (const int*)  d_in[0];
    const float* emb    = (const float*)d_in[1];
    const float* Wq     = (const float*)d_in[2];
    const float* bq_    = (const float*)d_in[3];
    const float* Wk     = (const float*)d_in[4];
    const float* bk_    = (const float*)d_in[5];
    const float* Wv     = (const float*)d_in[6];
    const float* bv_    = (const float*)d_in[7];
    const float* Wout   = (const float*)d_in[8];
    const float* bout_  = (const float*)d_in[9];
    float* out = (float*)d_out;

    bert_kernel<<<dim3(Bn / WPB), dim3(128), 0, stream>>>(
        tokens, emb, Wq, bq_, Wk, bk_, Wv, bv_, Wout, bout_, out);
}